// Round 8
// baseline (218.474 us; speedup 1.0000x reference)
//
#include <hip/hip_runtime.h>

// IntraClusterGAT on MI355X — Round 8 (= Round 7 with compile fix:
// update_dpp ctrl must be an immediate -> template parameter).
//   prep:  Mtr = (WQ^T WK/8)^T, Pbf = hw*Wout@WV (bf16, in ws)
//   attn:  gather fp32->bf16 Xc -> Zc=Xc@M (MFMA, M frags hoisted) ->
//          scores=Zc@Xc^T (MFMA) -> exp -> rowsum via DPP tree (+1 swizzle)
//          -> normalize -> E-half stores interleaved with GEMM3 halves
//          (B-frags via ds_read_u16) -> DPP-pair pack -> pk_add_bf16 scatter
//   final: out = x + (accum@P^T)/max(cnt,1) + b  (MFMA, A-frags from global)
//
// attn LDS = 37632B, 4 blocks/CU. DS instrs/wave ~295 (was ~390).

#define NV 100000
#define NN 200000
#define NCLUST 2048
#define XS 72    // Xc/Eh row stride (bf16): 144B, 16B-aligned

typedef __attribute__((ext_vector_type(8))) short short8;
typedef __attribute__((ext_vector_type(16))) float floatx16;

__device__ __forceinline__ unsigned short f2bf(float f) {
    union { float f; unsigned u; } v; v.f = f;
    unsigned r = v.u + 0x7fffu + ((v.u >> 16) & 1u);   // RNE
    return (unsigned short)(r >> 16);
}
__device__ __forceinline__ int crow(int r, int lane) {   // MFMA 32x32 C row map
    return (r & 3) + 8 * (r >> 2) + 4 * (lane >> 5);
}
template <int CTRL>
__device__ __forceinline__ float dpp_f(float v) {        // DPP-moved copy
    union { float f; int i; } a, b;
    a.f = v;
    b.i = __builtin_amdgcn_update_dpp(0, a.i, CTRL, 0xF, 0xF, false);
    return b.f;
}

__global__ __launch_bounds__(256) void prep_kernel(
    const float* __restrict__ WQ, const float* __restrict__ WK,
    const float* __restrict__ WV, const float* __restrict__ Wout,
    const float* __restrict__ head_weights, const int* __restrict__ active_heads_p,
    unsigned short* __restrict__ Mtr, unsigned short* __restrict__ Pbf)
{
    int o = blockIdx.x * blockDim.x + threadIdx.x;
    int ah = active_heads_p[0];
    float hw = 0.f;
    for (int i = 0; i < ah; ++i) hw += head_weights[i];
    hw /= (float)ah;
    if (o < 4096) {
        int d = o >> 6, a = o & 63;                       // Mtr[d][a] = M[a][d]
        float acc = 0.f;
        for (int j = 0; j < 64; ++j) acc += WQ[j*64 + a] * WK[j*64 + d];
        Mtr[o] = f2bf(acc * 0.125f);
    } else if (o < 8192) {
        int o2 = o - 4096;
        int j = o2 >> 6, b = o2 & 63;                     // Pbf[j][b]
        float acc = 0.f;
        for (int d = 0; d < 64; ++d) acc += Wout[j*64 + d] * WV[d*64 + b];
        Pbf[o2] = f2bf(acc * hw);
    }
}

__global__ __launch_bounds__(256, 4) void attn_kernel(
    const float* __restrict__ x_var, const float* __restrict__ x_clause,
    const int* __restrict__ cvar, const int* __restrict__ ccl,
    const float* __restrict__ sat, const unsigned short* __restrict__ Mtr,
    unsigned short* __restrict__ accum_bf, float* __restrict__ countv)
{
    __shared__ unsigned short Xc[128 * XS];   // 18432, persistent
    __shared__ unsigned short Eh[128 * XS];   // 18432, Zc then E-halves (wave-local rows)
    __shared__ int   ids[128];                //   512
    __shared__ float biascl[64];              //   256
    // total 37632 B -> 4 blocks/CU

    const int tid = threadIdx.x, lane = tid & 63, w = tid >> 6;
    const int c = blockIdx.x;
    const int m = lane & 31, hk = (lane >> 5) * 8;

    // M fragments hoisted: global loads in flight during the gather
    short8 mb0[4], mb1[4];
    #pragma unroll
    for (int ks = 0; ks < 4; ++ks) {
        mb0[ks] = *(const short8*)(Mtr + m * 64 + ks * 16 + hk);
        mb1[ks] = *(const short8*)(Mtr + (32 + m) * 64 + ks * 16 + hk);
    }

    // ---- gather: fp32 rows -> bf16 -> Xc row-major ----
    {
        const int r = tid >> 1, half = tid & 1;
        int nid;
        const float* src;
        if (r < 64) {
            nid = cvar[c * 64 + r];
            src = x_var + (size_t)nid * 64;
        } else {
            int cid = ccl[c * 64 + (r - 64)];
            nid = NV + cid;
            src = x_clause + (size_t)cid * 64;
            if (half) biascl[r - 64] = sat[cid];   // GAMMA = 1
        }
        if (!half) ids[r] = nid;
        union { unsigned short us[32]; short8 v[4]; } hb;
        const float4* s4 = (const float4*)src + half * 8;
        #pragma unroll
        for (int i = 0; i < 8; ++i) {
            float4 v = s4[i];
            hb.us[i*4+0] = f2bf(v.x); hb.us[i*4+1] = f2bf(v.y);
            hb.us[i*4+2] = f2bf(v.z); hb.us[i*4+3] = f2bf(v.w);
        }
        const int c0 = half * 32;
        #pragma unroll
        for (int i = 0; i < 4; ++i) *(short8*)&Xc[r * XS + c0 + i * 8] = hb.v[i];
    }
    __syncthreads();
    if (tid < 128) atomicAdd(&countv[ids[tid]], 1.0f);

    // ---- GEMM1: Zc = Xc @ M  (m-tile w, K=64) ----
    {
        floatx16 z0 = {}, z1 = {};
        #pragma unroll
        for (int ks = 0; ks < 4; ++ks) {
            short8 a = *(const short8*)&Xc[(w * 32 + m) * XS + ks * 16 + hk];
            z0 = __builtin_amdgcn_mfma_f32_32x32x16_bf16(a, mb0[ks], z0, 0, 0, 0);
            z1 = __builtin_amdgcn_mfma_f32_32x32x16_bf16(a, mb1[ks], z1, 0, 0, 0);
        }
        #pragma unroll
        for (int r = 0; r < 16; ++r) {     // wave-local rows 32w..32w+31
            int row = w * 32 + crow(r, lane);
            Eh[row * XS + m]      = f2bf(z0[r]);
            Eh[row * XS + 32 + m] = f2bf(z1[r]);
        }
    }

    // ---- GEMM2: scores = Zc @ Xc^T  (m-tile w, n-tiles 0..3, K=64) ----
    floatx16 sc[4] = {{}, {}, {}, {}};
    #pragma unroll
    for (int ks = 0; ks < 4; ++ks) {
        short8 a = *(const short8*)&Eh[(w * 32 + m) * XS + ks * 16 + hk];
        #pragma unroll
        for (int nt = 0; nt < 4; ++nt) {
            short8 b = *(const short8*)&Xc[(nt * 32 + m) * XS + ks * 16 + hk];
            sc[nt] = __builtin_amdgcn_mfma_f32_32x32x16_bf16(a, b, sc[nt], 0, 0, 0);
        }
    }

    // ---- bias + leaky_relu + exp + rowsum (DPP tree) + normalize ----
    const float b2 = biascl[m], b3 = biascl[32 + m];
    #pragma unroll
    for (int r = 0; r < 16; ++r) {
        float a0 = sc[0][r], a1 = sc[1][r], a2 = sc[2][r] + b2, a3 = sc[3][r] + b3;
        a0 = a0 > 0.f ? a0 : 0.2f * a0;
        a1 = a1 > 0.f ? a1 : 0.2f * a1;
        a2 = a2 > 0.f ? a2 : 0.2f * a2;
        a3 = a3 > 0.f ? a3 : 0.2f * a3;
        a0 = __expf(a0); a1 = __expf(a1); a2 = __expf(a2); a3 = __expf(a3);
        float s = (a0 + a1) + (a2 + a3);         // 32-col partial per lane
        s += dpp_f<0xB1>(s);                     // + lane^1   (quad_perm 1,0,3,2)
        s += dpp_f<0x4E>(s);                     // + lane^2   (quad_perm 2,3,0,1)
        s += dpp_f<0x141>(s);                    // + lane^4   (row_half_mirror)
        s += dpp_f<0x140>(s);                    // + lane^8   (row_mirror) -> 16-lane sum
        {                                        // + lane^16 within half-wave
            union { float f; int i; } u0, u1;
            u0.f = s;
            u1.i = __builtin_amdgcn_ds_swizzle(u0.i, 0x401F);  // xor 16
            s += u1.f;
        }
        float inv = __builtin_amdgcn_rcpf(s);    // full 128-col rowsum
        sc[0][r] = a0 * inv; sc[1][r] = a1 * inv;
        sc[2][r] = a2 * inv; sc[3][r] = a3 * inv;
    }

    // ---- E-half 1 (cols 0..63) over Zc rows (wave-local) ----
    #pragma unroll
    for (int r = 0; r < 16; ++r) {
        int row = w * 32 + crow(r, lane);
        Eh[row * XS + m]      = f2bf(sc[0][r]);
        Eh[row * XS + 32 + m] = f2bf(sc[1][r]);
    }

    // ---- GEMM3 half 1: t = 0..63 (B cols via ds_read_u16 from Xc) ----
    floatx16 g0 = {}, g1 = {};
    #pragma unroll
    for (int ks = 0; ks < 4; ++ks) {
        short8 a = *(const short8*)&Eh[(w * 32 + m) * XS + ks * 16 + hk];
        short8 b0, b1;
        #pragma unroll
        for (int j = 0; j < 8; ++j) {
            int t = ks * 16 + hk + j;
            b0[j] = (short)Xc[t * XS + m];
            b1[j] = (short)Xc[t * XS + 32 + m];
        }
        g0 = __builtin_amdgcn_mfma_f32_32x32x16_bf16(a, b0, g0, 0, 0, 0);
        g1 = __builtin_amdgcn_mfma_f32_32x32x16_bf16(a, b1, g1, 0, 0, 0);
    }

    // ---- E-half 2 (cols 64..127) ----
    #pragma unroll
    for (int r = 0; r < 16; ++r) {
        int row = w * 32 + crow(r, lane);
        Eh[row * XS + m]      = f2bf(sc[2][r]);
        Eh[row * XS + 32 + m] = f2bf(sc[3][r]);
    }

    // ---- GEMM3 half 2: t = 64..127 ----
    #pragma unroll
    for (int ks = 0; ks < 4; ++ks) {
        short8 a = *(const short8*)&Eh[(w * 32 + m) * XS + ks * 16 + hk];
        short8 b0, b1;
        #pragma unroll
        for (int j = 0; j < 8; ++j) {
            int t = 64 + ks * 16 + hk + j;
            b0[j] = (short)Xc[t * XS + m];
            b1[j] = (short)Xc[t * XS + 32 + m];
        }
        g0 = __builtin_amdgcn_mfma_f32_32x32x16_bf16(a, b0, g0, 0, 0, 0);
        g1 = __builtin_amdgcn_mfma_f32_32x32x16_bf16(a, b1, g1, 0, 0, 0);
    }

    // ---- DPP-pair pack + pk_add_bf16 scatter (pre-normalized) ----
    const bool ev = !(lane & 1);
    const int colbase = ev ? m : (31 + m);
    #pragma unroll
    for (int r = 0; r < 16; ++r) {
        int row = w * 32 + crow(r, lane);
        int nid = ids[row];
        float a0 = g0[r], a1 = g1[r];
        float t0 = dpp_f<0xB1>(a0);             // neighbor's col-m value
        float t1 = dpp_f<0xB1>(a1);             // neighbor's col-(32+m) value
        float lo = ev ? a0 : t1;
        float hi = ev ? t0 : a1;
        unsigned pk = (unsigned)f2bf(lo) | ((unsigned)f2bf(hi) << 16);
        unsigned long long addr =
            (unsigned long long)(accum_bf + (size_t)nid * 64 + colbase);
        asm volatile("global_atomic_pk_add_bf16 %0, %1, off"
                     :: "v"(addr), "v"(pk) : "memory");
    }
}

__global__ __launch_bounds__(256, 4) void finalize_kernel(
    const float* __restrict__ x_var, const float* __restrict__ x_clause,
    const unsigned short* __restrict__ accum_bf, const float* __restrict__ countv,
    const unsigned short* __restrict__ Pbf, const float* __restrict__ bout,
    float* __restrict__ out)
{
    __shared__ float cnts[256];
    const int tid = threadIdx.x, lane = tid & 63, w = tid >> 6;
    const int base = blockIdx.x * 256;
    {
        int n = base + tid;
        cnts[tid] = (n < NN) ? countv[n] : 1.f;
    }
    __syncthreads();

    const int m = lane & 31, hk = (lane >> 5) * 8;
    short8 pb[2][4];                              // P fragments via L1
    #pragma unroll
    for (int nt = 0; nt < 2; ++nt)
        #pragma unroll
        for (int ks = 0; ks < 4; ++ks)
            pb[nt][ks] = *(const short8*)(Pbf + (nt * 32 + m) * 64 + ks * 16 + hk);
    const float bias0 = bout[m], bias1 = bout[32 + m];

    #pragma unroll
    for (int tm = 0; tm < 2; ++tm) {
        int mt = w * 2 + tm;                      // rows base+mt*32 ..
        const unsigned short* arow = accum_bf + (size_t)(base + mt * 32 + m) * 64;
        floatx16 c0 = {}, c1 = {};
        #pragma unroll
        for (int ks = 0; ks < 4; ++ks) {
            short8 a = *(const short8*)(arow + ks * 16 + hk);
            c0 = __builtin_amdgcn_mfma_f32_32x32x16_bf16(a, pb[0][ks], c0, 0, 0, 0);
            c1 = __builtin_amdgcn_mfma_f32_32x32x16_bf16(a, pb[1][ks], c1, 0, 0, 0);
        }
        #pragma unroll
        for (int r = 0; r < 16; ++r) {
            int lrow = mt * 32 + crow(r, lane);
            int n = base + lrow;
            if (n < NN) {
                float inv = 1.0f / fmaxf(cnts[lrow], 1.0f);
                const float* xs = (n < NV) ? (x_var + (size_t)n * 64)
                                           : (x_clause + (size_t)(n - NV) * 64);
                out[(size_t)n * 64 + m]      = xs[m]      + c0[r] * inv + bias0;
                out[(size_t)n * 64 + 32 + m] = xs[32 + m] + c1[r] * inv + bias1;
            }
        }
    }
}

extern "C" void kernel_launch(void* const* d_in, const int* in_sizes, int n_in,
                              void* d_out, int out_size, void* d_ws, size_t ws_size,
                              hipStream_t stream)
{
    const float* x_var        = (const float*)d_in[0];
    const float* x_clause     = (const float*)d_in[1];
    const int*   cvar         = (const int*)d_in[4];
    const int*   ccl          = (const int*)d_in[5];
    const float* sat          = (const float*)d_in[6];
    const int*   active_heads = (const int*)d_in[7];
    const float* WQ           = (const float*)d_in[8];
    const float* WK           = (const float*)d_in[9];
    const float* WV           = (const float*)d_in[10];
    const float* head_weights = (const float*)d_in[11];
    const float* Wout         = (const float*)d_in[12];
    const float* bout         = (const float*)d_in[13];

    unsigned short* accum_bf = (unsigned short*)d_ws;          // NN*64 bf16
    float* countv = (float*)(accum_bf + (size_t)NN * 64);      // NN f32
    unsigned short* Mtr = (unsigned short*)(countv + NN);      // 4096 bf16
    unsigned short* Pbf = Mtr + 4096;                          // 4096 bf16

    (void)hipMemsetAsync(accum_bf, 0, (size_t)NN * 64 * 2 + (size_t)NN * 4, stream);
    prep_kernel<<<32, 256, 0, stream>>>(WQ, WK, WV, Wout, head_weights, active_heads, Mtr, Pbf);
    attn_kernel<<<NCLUST, 256, 0, stream>>>(x_var, x_clause, cvar, ccl, sat, Mtr, accum_bf, countv);
    finalize_kernel<<<(NN + 255) / 256, 256, 0, stream>>>(x_var, x_clause, accum_bf, countv, Pbf, bout, (float*)d_out);
}